// Round 8
// baseline (723.262 us; speedup 1.0000x reference)
//
#include <hip/hip_runtime.h>
#include <hip/hip_bf16.h>
#include <math.h>

#define N_NODES 20000
#define N_EDGES 320000
#define N_GRAPH 16
#define HID 256
#define NLAYER 4
#define NHEAD 4
#define DHEAD 64
#define EHID 16
#define NODE_DIMC 1280
#define EMLP_BLOCKS 1250   /* 1250*256 == 320000 exactly */
#define XLRS 512           /* stride of combined xl|xr buffer (in elements) */
#define TABN 4096          /* ep lookup-table knots (rows = TABN+1); nearest-knot lookup */

typedef short short8 __attribute__((ext_vector_type(8)));
typedef float f32x4 __attribute__((ext_vector_type(4)));

__device__ __forceinline__ float4 ld4(const float* p){ return *reinterpret_cast<const float4*>(p); }
__device__ __forceinline__ void st4(float* p, float4 v){ *reinterpret_cast<float4*>(p) = v; }
__device__ __forceinline__ float geluf(float x){ return 0.5f*x*(1.0f+erff(x*0.70710678118654752440f)); }
__device__ __forceinline__ float wsum64(float v){
  #pragma unroll
  for(int o=32;o;o>>=1) v += __shfl_xor(v,o,64);
  return v;
}
__device__ __forceinline__ float wmax64(float v){
  #pragma unroll
  for(int o=32;o;o>>=1) v = fmaxf(v, __shfl_xor(v,o,64));
  return v;
}
__device__ __forceinline__ int lbound(const int* __restrict__ a, int val){
  int lo=0, hi=N_NODES;
  while(lo<hi){ int mid=(lo+hi)>>1; if(a[mid]<val) lo=mid+1; else hi=mid; }
  return lo;
}
__device__ __forceinline__ short cvt_bf16(float f){
  __hip_bfloat16 h = __float2bfloat16(f);
  return *reinterpret_cast<short*>(&h);
}
__device__ __forceinline__ float bf2f(short s){
  return __uint_as_float(((unsigned)(unsigned short)s) << 16);
}
__device__ __forceinline__ float4 cvt4(short4 s){
  float4 r; r.x=bf2f(s.x); r.y=bf2f(s.y); r.z=bf2f(s.z); r.w=bf2f(s.w); return r;
}
__device__ __forceinline__ short4 f2s4(float4 v){
  short4 s; s.x=cvt_bf16(v.x); s.y=cvt_bf16(v.y); s.z=cvt_bf16(v.z); s.w=cvt_bf16(v.w); return s;
}
// async global->LDS, 16B per lane; LDS dest is wave-uniform base + lane*16
__device__ __forceinline__ void glds16(const short* g, short* l){
  __builtin_amdgcn_global_load_lds((const __attribute__((address_space(1))) void*)g,
                                   (__attribute__((address_space(3))) void*)l, 16, 0, 0);
}

// ---------------- fused weight prep + zero + x->bf16 (replaces 7 kernels) ----------------
// seg0 W_in_t 327680 | seg1 Wlr_t 524288 | seg2 Wg1_t 32768 | seg3 blr 2048 | seg4 W2e 16384
// seg5 be 1024 | seg6 zero cursor 20000 | seg7 zero pooled 4096 | seg8 xcvt 6400000 (short4 units)
#define PREP_W  904192
#define PREP_Z1 924192
#define PREP_Z2 928288
#define PREP_TOTAL 7328288
__global__ __launch_bounds__(256) void k_prep(const float* __restrict__ W_in, const float* __restrict__ Wl,
    const float* __restrict__ Wr, const float* __restrict__ Wg1, const float* __restrict__ bl,
    const float* __restrict__ br, const float* __restrict__ W2, const float* __restrict__ b2,
    const float* __restrict__ We, const float* __restrict__ x,
    short* __restrict__ W_in_t, short* __restrict__ Wlr_t, short* __restrict__ Wg1_t,
    float* __restrict__ blr, float* __restrict__ W2e, float* __restrict__ be,
    int* __restrict__ cursor, float* __restrict__ pooled, short* __restrict__ xb){
  int idx = blockIdx.x*256 + threadIdx.x;
  if(idx >= PREP_Z2){
    int t = idx - PREP_Z2;             // 6.4M float4s of x
    float4 v = ld4(x + (long)t*4);
    *(short4*)(xb + (long)t*4) = f2s4(v);
  } else if(idx < 327680){
    int n = idx / 1280, k = idx - n*1280;
    W_in_t[idx] = cvt_bf16(W_in[(long)k*256 + n]);
  } else if(idx < 851968){
    int t = idx - 327680;
    int l = t >> 17; int rem = t & 131071; int n = rem >> 8, k = rem & 255;
    const float* W = (n < 256) ? (Wl + (long)l*65536 + (long)k*256 + n)
                               : (Wr + (long)l*65536 + (long)k*256 + (n-256));
    Wlr_t[t] = cvt_bf16(*W);
  } else if(idx < 884736){
    int t = idx - 851968;
    int n = t >> 8, k = t & 255;
    Wg1_t[t] = cvt_bf16(Wg1[(long)k*128 + n]);
  } else if(idx < 886784){
    int t = idx - 884736;
    int l = t >> 9, c = t & 511;
    blr[t] = (c < 256) ? bl[l*256 + c] : br[l*256 + c - 256];
  } else if(idx < 903168){
    int t = idx - 886784;
    int l = t >> 12; int rem = t & 4095; int k = rem >> 8, dd = rem & 255;
    float s = 0.f;
    #pragma unroll
    for(int j=0;j<16;j++) s += W2[k*16+j]*We[l*4096 + j*256 + dd];
    W2e[t] = s;
  } else if(idx < PREP_W){
    int t = idx - 903168;
    int l = t >> 8, dd = t & 255;
    float s = 0.f;
    #pragma unroll
    for(int j=0;j<16;j++) s += b2[j]*We[l*4096 + j*256 + dd];
    be[t] = s;
  } else if(idx < PREP_Z1){
    cursor[idx - PREP_W] = 0;
  } else {
    pooled[idx - PREP_Z1] = 0.f;
  }
}

// ---------------- ep lookup table ----------------
__global__ __launch_bounds__(256) void k_etab(const float* __restrict__ W1, const float* __restrict__ b1,
                      const float* __restrict__ W2e, const float* __restrict__ be,
                      short* __restrict__ tab){
  __shared__ float t[16];
  int idx = blockIdx.x, l = blockIdx.y, d = threadIdx.x;
  if(d < 16) t[d] = geluf(((float)idx*(1.0f/TABN))*W1[d] + b1[d]);
  __syncthreads();
  float s = be[l*256 + d];
  #pragma unroll
  for(int k=0;k<16;k++) s += t[k]*W2e[(l*16+k)*256 + d];
  tab[((long)l*(TABN+1) + idx)*256 + d] = cvt_bf16(s);
}

// ---------------- single-shot K=256 GEMM (no inner barriers) ----------------
// Mechanism: at K=256 the looped GEMM pays 16 barrier-pairs + vmcnt waits for only 8 MFMA
// phases (m233: 2-phase structure ~72% stage/barrier overhead). Here the ENTIRE K is staged
// once (As 64KB + Bs 64KB = 128KB LDS), one vmcnt(0)+barrier, then 128 MFMAs barrier-free
// (compiler emits fine-grained lgkmcnt for ds_read->MFMA). Fragment addressing identical to
// the proven looped kernel -> bit-identical results.
// OUTB: 1 = bf16 C via LDS-coalesced stores, 2 = gate mode (N=128)
template<int OUTB>
__global__ __launch_bounds__(256) void k_gemm1(const short* __restrict__ A,
    const short* __restrict__ Bt, const float* __restrict__ bias,
    short* __restrict__ Cb,
    const float* __restrict__ Wg2, const float* __restrict__ bg2, float* __restrict__ gate,
    int M, int ldc){
  const int K = 256;
  __shared__ short As[8*128*32];   // 64KB, [slice kk][row 128][32 shorts]
  __shared__ short Bs[8*128*32];   // 64KB
  int tid = threadIdx.x;
  int w = tid>>6, lane = tid&63;
  int g = lane>>4, m = lane&15;
  int bm = blockIdx.x*128, bn = blockIdx.y*128;
  int crow = lane>>2;
  int coff = (lane&3)*8;
  int ar0 = bm + (w*2+0)*16 + crow; ar0 = ar0 < M ? ar0 : M-1;
  int ar1 = bm + (w*2+1)*16 + crow; ar1 = ar1 < M ? ar1 : M-1;
  const short* Ap0 = A + (long)ar0*K + coff;
  const short* Ap1 = A + (long)ar1*K + coff;
  const short* Bp0 = Bt + (long)(bn + (w*2+0)*16 + crow)*K + coff;
  const short* Bp1 = Bt + (long)(bn + (w*2+1)*16 + crow)*K + coff;
  short* As0 = &As[(w*2+0)*512]; short* As1 = &As[(w*2+1)*512];
  short* Bs0 = &Bs[(w*2+0)*512]; short* Bs1 = &Bs[(w*2+1)*512];
  // stage all 8 K-slices (32 glds16/wave, all in flight)
  #pragma unroll
  for(int kk=0;kk<8;kk++){
    glds16(Ap0 + kk*32, As0 + kk*4096);
    glds16(Ap1 + kk*32, As1 + kk*4096);
    glds16(Bp0 + kk*32, Bs0 + kk*4096);
    glds16(Bp1 + kk*32, Bs1 + kk*4096);
  }
  f32x4 acc[2][8];
  #pragma unroll
  for(int i=0;i<2;i++)
    #pragma unroll
    for(int j=0;j<8;j++) acc[i][j] = (f32x4){0.f,0.f,0.f,0.f};
  __builtin_amdgcn_s_waitcnt(0x0F70);   // vmcnt(0): all staging done
  __builtin_amdgcn_s_barrier();
  #pragma unroll
  for(int kk=0;kk<8;kk++){
    const short* ab = &As[kk*4096];
    const short* bb = &Bs[kk*4096];
    short8 a0 = *(const short8*)&ab[(w*32 + m)*32 + g*8];
    short8 a1 = *(const short8*)&ab[(w*32 + 16 + m)*32 + g*8];
    #pragma unroll
    for(int j=0;j<8;j++){
      short8 bf = *(const short8*)&bb[(j*16 + m)*32 + g*8];
      acc[0][j] = __builtin_amdgcn_mfma_f32_16x16x32_bf16(a0, bf, acc[0][j], 0,0,0);
      acc[1][j] = __builtin_amdgcn_mfma_f32_16x16x32_bf16(a1, bf, acc[1][j], 0,0,0);
    }
  }
  if(OUTB == 2){
    float bg2v = bg2[0];
    #pragma unroll
    for(int mi=0;mi<2;mi++){
      float part[4] = {0.f,0.f,0.f,0.f};
      #pragma unroll
      for(int j=0;j<8;j++){
        int col = j*16 + m;
        float wg = Wg2[col];
        float bv = bias[col];
        #pragma unroll
        for(int r=0;r<4;r++) part[r] += tanhf(acc[mi][j][r] + bv) * wg;
      }
      #pragma unroll
      for(int r=0;r<4;r++){
        #pragma unroll
        for(int o=1;o<16;o<<=1) part[r] += __shfl_xor(part[r], o, 16);
      }
      if(m == 0){
        #pragma unroll
        for(int r=0;r<4;r++){
          int row = bm + w*32 + mi*16 + g*4 + r;
          if(row < M) gate[row] = part[r] + bg2v;
        }
      }
    }
  } else {
    // waves are unsynced after the barrier-free loop; sync before reusing As as C-tile scratch
    __syncthreads();
    #pragma unroll
    for(int mi=0;mi<2;mi++){
      int rl0 = w*32 + mi*16 + g*4;
      #pragma unroll
      for(int j=0;j<8;j++){
        int col = j*16 + m;
        float bv = bias[bn + col];
        #pragma unroll
        for(int r=0;r<4;r++)
          As[(rl0 + r)*132 + col] = cvt_bf16(acc[mi][j][r] + bv);
      }
    }
    __syncthreads();
    int lr = tid >> 4, lc = (tid & 15)*8;
    #pragma unroll
    for(int p=0;p<8;p++){
      int row = bm + p*16 + lr;
      if(row < M){
        short8 v = *(const short8*)&As[(p*16 + lr)*132 + lc];
        *(short8*)&Cb[(long)row*ldc + bn + lc] = v;
      }
    }
  }
}

// ---------------- pipelined bf16 GEMM (K=1280 input proj; triple buffer, counted vmcnt) ----------------
// OUTB: 0 = fp32 C (only mode used)
template<int OUTB>
__global__ __launch_bounds__(256) void k_gemm_p(const short* __restrict__ A,
    const short* __restrict__ Bt, const float* __restrict__ bias,
    float* __restrict__ Cf, short* __restrict__ Cb,
    int M, int K, int ldc){
  __shared__ short smem[24576];   // 48KB: As 3 bufs | Bs 3 bufs
  short* Asb = smem;
  short* Bsb = smem + 12288;
  int tid = threadIdx.x;
  int w = tid>>6, lane = tid&63;
  int g = lane>>4, m = lane&15;
  int bm = blockIdx.x*128, bn = blockIdx.y*128;
  int crow = lane>>2;
  int coff = (lane&3)*8;
  int ar0 = bm + (w*2+0)*16 + crow; ar0 = ar0 < M ? ar0 : M-1;
  int ar1 = bm + (w*2+1)*16 + crow; ar1 = ar1 < M ? ar1 : M-1;
  const short* Ap0 = A + (long)ar0*K + coff;
  const short* Ap1 = A + (long)ar1*K + coff;
  const short* Bp0 = Bt + (long)(bn + (w*2+0)*16 + crow)*K + coff;
  const short* Bp1 = Bt + (long)(bn + (w*2+1)*16 + crow)*K + coff;
  short* As0 = Asb + (w*2+0)*512; short* As1 = Asb + (w*2+1)*512;
  short* Bs0 = Bsb + (w*2+0)*512; short* Bs1 = Bsb + (w*2+1)*512;
  const int bufstride = 128*32;
  f32x4 acc[2][8];
  #pragma unroll
  for(int i=0;i<2;i++)
    #pragma unroll
    for(int j=0;j<8;j++) acc[i][j] = (f32x4){0.f,0.f,0.f,0.f};
  int niter = K >> 5;
  glds16(Ap0, As0); glds16(Ap1, As1); glds16(Bp0, Bs0); glds16(Bp1, Bs1);
  if(niter > 1){
    glds16(Ap0+32, As0+bufstride); glds16(Ap1+32, As1+bufstride);
    glds16(Bp0+32, Bs0+bufstride); glds16(Bp1+32, Bs1+bufstride);
  }
  for(int i=0;i<niter;i++){
    int cur = i % 3;
    if(i+2 < niter){
      int k = (i+2)<<5;
      int nb = (i+2) % 3;
      glds16(Ap0 + k, As0 + nb*bufstride);
      glds16(Ap1 + k, As1 + nb*bufstride);
      glds16(Bp0 + k, Bs0 + nb*bufstride);
      glds16(Bp1 + k, Bs1 + nb*bufstride);
      __builtin_amdgcn_s_waitcnt(0x0F78);   // vmcnt(8)
    } else if(i+1 < niter){
      __builtin_amdgcn_s_waitcnt(0x0F74);   // vmcnt(4)
    } else {
      __builtin_amdgcn_s_waitcnt(0x0F70);   // vmcnt(0)
    }
    __builtin_amdgcn_s_barrier();
    const short* ab = Asb + cur*bufstride;
    const short* bb = Bsb + cur*bufstride;
    short8 a0 = *(const short8*)&ab[(w*32 + m)*32 + g*8];
    short8 a1 = *(const short8*)&ab[(w*32 + 16 + m)*32 + g*8];
    #pragma unroll
    for(int j=0;j<8;j++){
      short8 bf = *(const short8*)&bb[(j*16 + m)*32 + g*8];
      acc[0][j] = __builtin_amdgcn_mfma_f32_16x16x32_bf16(a0, bf, acc[0][j], 0,0,0);
      acc[1][j] = __builtin_amdgcn_mfma_f32_16x16x32_bf16(a1, bf, acc[1][j], 0,0,0);
    }
    __builtin_amdgcn_s_barrier();
  }
  #pragma unroll
  for(int mi=0;mi<2;mi++){
    int r0 = bm + w*32 + mi*16 + g*4;
    #pragma unroll
    for(int j=0;j<8;j++){
      int col = bn + j*16 + m;
      float bv = bias[col];
      #pragma unroll
      for(int r=0;r<4;r++){
        int row = r0 + r;
        if(row < M) Cf[(long)row*ldc + col] = acc[mi][j][r] + bv;
      }
    }
  }
}

// ---------------- LayerNorm + GELU (input proj epilogue); writes fp32 h + bf16 h ----------------
__global__ __launch_bounds__(256) void k_ln_gelu(const float* __restrict__ in, const float* __restrict__ g,
                          const float* __restrict__ b, float* __restrict__ out, short* __restrict__ outb){
  int gw = (int)((blockIdx.x * blockDim.x + threadIdx.x) >> 6);
  int lane = threadIdx.x & 63;
  if (gw >= N_NODES) return;
  long base = (long)gw*HID + lane*4;
  float4 v = ld4(in + base);
  float mu = wsum64(v.x+v.y+v.z+v.w) * (1.0f/HID);
  float dx=v.x-mu, dy=v.y-mu, dz=v.z-mu, dw=v.w-mu;
  float var = wsum64(dx*dx+dy*dy+dz*dz+dw*dw) * (1.0f/HID);
  float r = rsqrtf(var + 1e-5f);
  float4 gg = ld4(g + lane*4), bb = ld4(b + lane*4);
  float4 o;
  o.x = geluf(dx*r*gg.x + bb.x);
  o.y = geluf(dy*r*gg.y + bb.y);
  o.z = geluf(dz*r*gg.z + bb.z);
  o.w = geluf(dw*r*gg.w + bb.w);
  st4(out + base, o);
  *(short4*)(outb + base) = f2s4(o);
}

// ---------------- edge MLP t-partials only (mean path) ----------------
__global__ __launch_bounds__(256) void k_edge_mlp(const float* __restrict__ ea, const float* __restrict__ W1,
                          const float* __restrict__ b1, float* __restrict__ epart){
  __shared__ float sW1[16], sB1[16];
  __shared__ float red[4][16];
  int tid = threadIdx.x;
  if(tid<16){ sW1[tid]=W1[tid]; sB1[tid]=b1[tid]; }
  __syncthreads();
  int e = blockIdx.x*256 + tid;
  float u = ea[e];
  int wv = tid>>6, lane = tid&63;
  #pragma unroll
  for(int j=0;j<16;j++){
    float t = geluf(u*sW1[j] + sB1[j]);
    float r = wsum64(t);
    if(lane == 0) red[wv][j] = r;
  }
  __syncthreads();
  if(tid < 16) epart[blockIdx.x*16 + tid] = red[0][tid]+red[1][tid]+red[2][tid]+red[3][tid];
}

// ---------------- reduce t-partials -> e_mean -> ep_loop[l] ----------------
__global__ __launch_bounds__(256) void k_const(const float* __restrict__ epart, const float* __restrict__ W2,
                       const float* __restrict__ b2, const float* __restrict__ We,
                       float* __restrict__ eploop){
  __shared__ float red[16][16];
  __shared__ float em[16];
  int tid = threadIdx.x;
  int j = tid & 15, p0 = tid >> 4;
  float s = 0.f;
  for(int p = p0; p < EMLP_BLOCKS; p += 16) s += epart[p*16 + j];
  red[p0][j] = s;
  __syncthreads();
  if(tid < 16){
    #pragma unroll
    for(int k=0;k<16;k++){
      float t = 0.f;
      #pragma unroll
      for(int q=0;q<16;q++) t += red[q][k];
      red[0][k] = t * (1.0f/N_EDGES);
    }
  }
  __syncthreads();
  if(tid < 16){
    float acc = b2[tid];
    #pragma unroll
    for(int k=0;k<16;k++) acc += red[0][k]*W2[k*16 + tid];
    em[tid] = acc;
  }
  __syncthreads();
  for(int l=0;l<NLAYER;l++){
    float acc = 0.f;
    #pragma unroll
    for(int k=0;k<16;k++) acc += em[k]*We[l*EHID*HID + k*HID + tid];
    eploop[l*HID + tid] = acc;
  }
}

__global__ __launch_bounds__(256) void k_csr_count(const int* __restrict__ ei, int* __restrict__ counts){
  int e = blockIdx.x*256 + threadIdx.x;
  if(e < N_EDGES) atomicAdd(&counts[ei[N_EDGES + e]], 1);
}

__global__ __launch_bounds__(1024) void k_csr_scan(const int* __restrict__ counts, int* __restrict__ offs,
                                                   int* __restrict__ cursor){
  __shared__ int part[1024];
  int t = threadIdx.x;
  const int chunk = (N_NODES + 1023) / 1024;
  int b0 = t * chunk;
  int s = 0;
  for(int i=0;i<chunk;i++){ int idx=b0+i; if(idx<N_NODES) s += counts[idx]; }
  part[t] = s;
  __syncthreads();
  for(int off=1; off<1024; off<<=1){
    int v = part[t];
    int add = (t>=off) ? part[t-off] : 0;
    __syncthreads();
    part[t] = v + add;
    __syncthreads();
  }
  int run = (t==0) ? 0 : part[t-1];
  for(int i=0;i<chunk;i++){
    int idx = b0+i;
    if(idx < N_NODES){
      int c = counts[idx];
      offs[idx] = run; cursor[idx] = run;
      run += c;
    }
  }
  if(t == 1023) offs[N_NODES] = part[1023];
}

// meta stores BYTE offsets: x = src*1024 (xlr row), y = i0*512 (tab row).
__global__ __launch_bounds__(256) void k_csr_fill(const int* __restrict__ ei, const float* __restrict__ ea,
                          int* __restrict__ cursor, int2* __restrict__ meta){
  int e = blockIdx.x*256 + threadIdx.x;
  if(e >= N_EDGES) return;
  int d = ei[N_EDGES + e];
  int pos = atomicAdd(&cursor[d], 1);
  float u = ea[e];
  int i0 = (int)(u * (float)TABN + 0.5f);
  meta[pos] = make_int2(ei[e] << 10, i0 << 9);
}

// ---------------- fused per-layer: 4-deep pipelined gather + nearest-knot ep + batched online softmax ----------------
__global__ __launch_bounds__(256) void k_layer(
    const short* __restrict__ xlr, float* __restrict__ h, short* __restrict__ hb,
    const short* __restrict__ tab_l,
    const float* __restrict__ eploop_l, const float* __restrict__ att_l,
    const int* __restrict__ offs, const int2* __restrict__ meta,
    const float* __restrict__ bconv_l, const float* __restrict__ g_l,
    const float* __restrict__ b_l){
  int tid = threadIdx.x;
  int lane = tid & 63;
  int d = blockIdx.x*4 + (tid >> 6);
  float4 at4 = ld4(att_l + lane*4);
  float4 epl = ld4(eploop_l + lane*4);
  const short4* xp = (const short4*)(xlr + (long)d*XLRS);
  float4 xld = cvt4(xp[lane]);
  float4 xr4 = cvt4(xp[64 + lane]);
  long hbase = (long)d*HID + lane*4;
  float4 h4 = ld4(h + hbase);
  int beg = offs[d], end = offs[d+1];

  const char* xlrb = (const char*)xlr + (lane<<3);
  const char* tabb = (const char*)tab_l + (lane<<3);

  short4 xsb0, xsb1, xsb2, xsb3, ta0, ta1, ta2, ta3;
  auto issue = [&](short4 &xsb, short4 &ta, int j){
    int2 mm = meta[j];
    xsb = *(const short4*)(xlrb + mm.x);
    ta  = *(const short4*)(tabb + mm.y);
  };
  auto logit = [&](short4 xsbv, short4 tav, float4 &xsf)->float{
    xsf = cvt4(xsbv);
    float4 t0 = cvt4(tav);
    float mx = xsf.x + xr4.x + t0.x; mx = fmaxf(mx, 0.2f*mx);
    float my = xsf.y + xr4.y + t0.y; my = fmaxf(my, 0.2f*my);
    float mz = xsf.z + xr4.z + t0.z; mz = fmaxf(mz, 0.2f*mz);
    float mw = xsf.w + xr4.w + t0.w; mw = fmaxf(mw, 0.2f*mw);
    float q = mx*at4.x + my*at4.y + mz*at4.z + mw*at4.w;
    q += __shfl_xor(q, 1, 16);
    q += __shfl_xor(q, 2, 16);
    q += __shfl_xor(q, 4, 16);
    q += __shfl_xor(q, 8, 16);
    return q;
  };

  float m_run, den;
  float4 acc;
  auto upd = [&](float q, float4 xs){
    if(q > m_run + 8.f){
      float sc = __expf(m_run - q);
      den *= sc;
      acc.x *= sc; acc.y *= sc; acc.z *= sc; acc.w *= sc;
      m_run = q;
    }
    float pe = __expf(q - m_run);
    den += pe;
    acc.x += pe*xs.x;
    acc.y += pe*xs.y;
    acc.z += pe*xs.z;
    acc.w += pe*xs.w;
  };

  int i = beg;
  if(beg < end){
    int e1 = (beg+1 < end) ? beg+1 : end-1;
    int e2 = (beg+2 < end) ? beg+2 : end-1;
    int e3 = (beg+3 < end) ? beg+3 : end-1;
    issue(xsb0, ta0, beg);
    issue(xsb1, ta1, e1);
    issue(xsb2, ta2, e2);
    issue(xsb3, ta3, e3);
  }
  float ax = xld.x + xr4.x + epl.x; ax = fmaxf(ax, 0.2f*ax);
  float ay = xld.y + xr4.y + epl.y; ay = fmaxf(ay, 0.2f*ay);
  float az = xld.z + xr4.z + epl.z; az = fmaxf(az, 0.2f*az);
  float aw = xld.w + xr4.w + epl.w; aw = fmaxf(aw, 0.2f*aw);
  float p = ax*at4.x + ay*at4.y + az*at4.z + aw*at4.w;
  p += __shfl_xor(p, 1, 16);
  p += __shfl_xor(p, 2, 16);
  p += __shfl_xor(p, 4, 16);
  p += __shfl_xor(p, 8, 16);
  m_run = p;
  den = 1.f;
  acc = xld;

  for(; i+3 < end; i += 4){
    float4 xs0, xs1, xs2, xs3;
    float q0 = logit(xsb0, ta0, xs0);
    float q1 = logit(xsb1, ta1, xs1);
    float q2 = logit(xsb2, ta2, xs2);
    float q3 = logit(xsb3, ta3, xs3);
    int j0 = (i+4 < end) ? i+4 : end-1;
    int j1 = (i+5 < end) ? i+5 : end-1;
    int j2 = (i+6 < end) ? i+6 : end-1;
    int j3 = (i+7 < end) ? i+7 : end-1;
    issue(xsb0, ta0, j0);
    issue(xsb1, ta1, j1);
    issue(xsb2, ta2, j2);
    issue(xsb3, ta3, j3);
    float pmax = fmaxf(fmaxf(q0,q1), fmaxf(q2,q3));
    if(pmax > m_run + 8.f){
      float sc = __expf(m_run - pmax);
      den *= sc;
      acc.x *= sc; acc.y *= sc; acc.z *= sc; acc.w *= sc;
      m_run = pmax;
    }
    float p0 = __expf(q0 - m_run), p1 = __expf(q1 - m_run);
    float p2 = __expf(q2 - m_run), p3 = __expf(q3 - m_run);
    den += (p0+p1)+(p2+p3);
    acc.x += p0*xs0.x + p1*xs1.x + p2*xs2.x + p3*xs3.x;
    acc.y += p0*xs0.y + p1*xs1.y + p2*xs2.y + p3*xs3.y;
    acc.z += p0*xs0.z + p1*xs1.z + p2*xs2.z + p3*xs3.z;
    acc.w += p0*xs0.w + p1*xs1.w + p2*xs2.w + p3*xs3.w;
  }
  int rem = end - i;
  if(rem > 0){ float4 xs; float q = logit(xsb0, ta0, xs); upd(q, xs); }
  if(rem > 1){ float4 xs; float q = logit(xsb1, ta1, xs); upd(q, xs); }
  if(rem > 2){ float4 xs; float q = logit(xsb2, ta2, xs); upd(q, xs); }

  float inv = 1.f/den;
  float4 bc4 = ld4(bconv_l + lane*4);
  float4 gg4 = ld4(g_l + lane*4);
  float4 bb4 = ld4(b_l + lane*4);
  float yx = geluf(acc.x*inv + bc4.x) + h4.x;
  float yy = geluf(acc.y*inv + bc4.y) + h4.y;
  float yz = geluf(acc.z*inv + bc4.z) + h4.z;
  float yw = geluf(acc.w*inv + bc4.w) + h4.w;
  float mu = wsum64(yx+yy+yz+yw) * (1.0f/HID);
  float dx=yx-mu, dy=yy-mu, dz=yz-mu, dw=yw-mu;
  float var = wsum64(dx*dx+dy*dy+dz*dz+dw*dw) * (1.0f/HID);
  float r = rsqrtf(var + 1e-5f);
  float4 o;
  o.x = dx*r*gg4.x + bb4.x;
  o.y = dy*r*gg4.y + bb4.y;
  o.z = dz*r*gg4.z + bb4.z;
  o.w = dw*r*gg4.w + bb4.w;
  st4(h + hbase, o);
  *(short4*)(hb + hbase) = f2s4(o);
}

// ---------------- per-graph softmax stats ----------------
__global__ __launch_bounds__(256) void k_gsm(const float* __restrict__ gate, const int* __restrict__ batch,
                     float* __restrict__ gmax, float* __restrict__ gden){
  __shared__ int sr[2];
  __shared__ float red[4];
  int g = blockIdx.x, tid = threadIdx.x;
  if(tid == 0){ sr[0] = lbound(batch, g); sr[1] = lbound(batch, g+1); }
  __syncthreads();
  int r0 = sr[0], r1 = sr[1];
  float mx = -3.4e38f;
  for(int v = r0 + tid; v < r1; v += 256) mx = fmaxf(mx, gate[v]);
  mx = wmax64(mx);
  if((tid&63)==0) red[tid>>6] = mx;
  __syncthreads();
  float m = fmaxf(fmaxf(red[0],red[1]), fmaxf(red[2],red[3]));
  float s = 0.f;
  for(int v = r0 + tid; v < r1; v += 256) s += __expf(gate[v] - m);
  s = wsum64(s);
  if((tid&63)==0) red[tid>>6] = s;
  __syncthreads();
  if(tid == 0){
    gmax[g] = m;
    gden[g] = red[0]+red[1]+red[2]+red[3];
  }
}

// ---------------- pooled[g] += w[v]*h[v] ----------------
__global__ __launch_bounds__(256) void k_gpool(const float* __restrict__ h, const float* __restrict__ gate,
                       const float* __restrict__ gmax, const float* __restrict__ gden,
                       const int* __restrict__ batch, float* __restrict__ pooled){
  __shared__ int sr[2];
  int g = blockIdx.y, c = threadIdx.x;
  if(c == 0){ sr[0] = lbound(batch, g); sr[1] = lbound(batch, g+1); }
  __syncthreads();
  int r0 = sr[0], r1 = sr[1];
  float m = gmax[g], inv = 1.f/gden[g];
  float acc = 0.f;
  for(int v = r0 + blockIdx.x; v < r1; v += 16){
    float w = __expf(gate[v] - m) * inv;
    acc += w * h[(long)v*HID + c];
  }
  atomicAdd(&pooled[g*HID + c], acc);
}

__global__ __launch_bounds__(64) void k_head(const float* __restrict__ pooled, const float* __restrict__ Wh1,
                      const float* __restrict__ bh1, const float* __restrict__ Wh2,
                      const float* __restrict__ bh2, float* __restrict__ out){
  __shared__ float sp[HID];
  int b = blockIdx.x, t = threadIdx.x;
  #pragma unroll
  for(int i=0;i<4;i++) sp[t + i*64] = pooled[b*HID + t + i*64];
  __syncthreads();
  float acc = bh1[t];
  #pragma unroll 8
  for(int k=0;k<HID;k++) acc += sp[k]*Wh1[k*64 + t];
  float g = geluf(acc);
  float contrib = g * Wh2[t];
  float r = wsum64(contrib);
  if(t==0) out[b] = r + bh2[0];
}

extern "C" void kernel_launch(void* const* d_in, const int* in_sizes, int n_in,
                              void* d_out, int out_size, void* d_ws, size_t ws_size,
                              hipStream_t stream) {
  const float* x        = (const float*)d_in[0];
  const float* edge_attr= (const float*)d_in[1];
  const float* W_in     = (const float*)d_in[2];
  const float* b_in     = (const float*)d_in[3];
  const float* ln_in_g  = (const float*)d_in[4];
  const float* ln_in_b  = (const float*)d_in[5];
  const float* W_e1     = (const float*)d_in[6];
  const float* b_e1     = (const float*)d_in[7];
  const float* W_e2     = (const float*)d_in[8];
  const float* b_e2     = (const float*)d_in[9];
  const float* Wl       = (const float*)d_in[10];
  const float* bl       = (const float*)d_in[11];
  const float* Wr       = (const float*)d_in[12];
  const float* br       = (const float*)d_in[13];
  const float* att      = (const float*)d_in[14];
  const float* We       = (const float*)d_in[15];
  const float* bconv    = (const float*)d_in[16];
  const float* ln_g     = (const float*)d_in[17];
  const float* ln_b     = (const float*)d_in[18];
  const float* Wg1      = (const float*)d_in[19];
  const float* bg1      = (const float*)d_in[20];
  const float* Wg2      = (const float*)d_in[21];
  const float* bg2      = (const float*)d_in[22];
  const float* Wh1      = (const float*)d_in[23];
  const float* bh1      = (const float*)d_in[24];
  const float* Wh2      = (const float*)d_in[25];
  const float* bh2      = (const float*)d_in[26];
  const int*   ei       = (const int*)d_in[27];
  const int*   batch    = (const int*)d_in[28];
  float* out = (float*)d_out;

  // ---- workspace layout (float offsets). x_bf16 (10.24M..23.04M) is dead after input GEMM;
  // only buf_xlr / buf_tab / buf_hb (first written after it) overlap that region.
  float* ws = (float*)d_ws;
  float* buf_h     = ws;                         // 0 .. 5.12M
  float* buf_t     = ws + 5120000;               // 5.12M .. 10.24M (input-proj tmp)
  short* buf_xlr   = (short*)(ws + 10240000);    // N*512 bf16
  short* x_bf16    = (short*)(ws + 10240000);    // 25.6M shorts -> ends 23.04M
  short* buf_tab   = (short*)(ws + 15360000);    // 4*4097*256 bf16
  short* buf_hb    = (short*)(ws + 17460000);    // N*256 bf16
  float* buf_eploop= ws + 23040000;              // 1024
  float* buf_gate  = ws + 23041024;              // 20000
  float* buf_gmax  = ws + 23061024;              // 16
  float* buf_gden  = ws + 23061040;              // 16
  float* buf_pooled= ws + 23061056;              // 4096
  float* buf_epart = ws + 23065200;              // 20000
  int*   csr_offs  = (int*)(ws + 23085200);      // 20001
  int*   csr_cursor= (int*)(ws + 23105204);      // 20000
  int2*  csr_meta  = (int2*)(ws + 23125204);     // 320000 int2
  short* W_in_t    = (short*)(ws + 23765204);    // 327,680 shorts
  short* Wlr_t     = (short*)(ws + 23929044);    // 524,288 shorts
  short* Wg1_t     = (short*)(ws + 24191188);    // 32,768 shorts
  float* buf_blr   = ws + 24207572;              // 2048
  float* buf_W2e   = ws + 24209620;              // 16384
  float* buf_be    = ws + 24226004;              // 1024

  // fused weight prep + zero + x->bf16
  k_prep<<<(PREP_TOTAL+255)/256,256,0,stream>>>(W_in, Wl, Wr, Wg1, bl, br, W_e2, b_e2, We, x,
                                                W_in_t, Wlr_t, Wg1_t, buf_blr, buf_W2e, buf_be,
                                                csr_cursor, buf_pooled, x_bf16);
  k_csr_count<<<(N_EDGES+255)/256,256,0,stream>>>(ei, csr_cursor);
  k_csr_scan<<<1,1024,0,stream>>>(csr_cursor, csr_offs, csr_cursor);
  k_csr_fill<<<(N_EDGES+255)/256,256,0,stream>>>(ei, edge_attr, csr_cursor, csr_meta);

  // input proj (K=1280, looped GEMM), then LN+GELU epilogue
  k_gemm_p<0><<<dim3(157,2),256,0,stream>>>(x_bf16, W_in_t, b_in, buf_t, nullptr,
                                            N_NODES, NODE_DIMC, 256);
  k_ln_gelu<<<(N_NODES+3)/4,256,0,stream>>>(buf_t, ln_in_g, ln_in_b, buf_h, buf_hb);
  k_etab<<<dim3(TABN+1,NLAYER),256,0,stream>>>(W_e1, b_e1, buf_W2e, buf_be, buf_tab);
  k_edge_mlp<<<EMLP_BLOCKS,256,0,stream>>>(edge_attr, W_e1, b_e1, buf_epart);
  k_const<<<1,256,0,stream>>>(buf_epart, W_e2, b_e2, We, buf_eploop);

  for(int l=0;l<NLAYER;l++){
    k_gemm1<1><<<dim3(157,4),256,0,stream>>>(buf_hb, Wlr_t + (long)l*131072,
                       buf_blr + l*512, buf_xlr,
                       nullptr, nullptr, nullptr, N_NODES, XLRS);
    k_layer<<<5000,256,0,stream>>>(buf_xlr, buf_h, buf_hb, buf_tab + (long)l*(TABN+1)*256,
                       buf_eploop + l*HID, att + l*NHEAD*DHEAD,
                       csr_offs, csr_meta, bconv + l*HID, ln_g + l*HID, ln_b + l*HID);
  }

  // gate: single-shot GEMM with fused tanh/Wg2 epilogue
  k_gemm1<2><<<dim3(157,1),256,0,stream>>>(buf_hb, Wg1_t, bg1, nullptr,
                                           Wg2, bg2, buf_gate, N_NODES, 0);
  k_gsm<<<N_GRAPH,256,0,stream>>>(buf_gate, batch, buf_gmax, buf_gden);
  dim3 gP(16, N_GRAPH);
  k_gpool<<<gP,256,0,stream>>>(buf_h, buf_gate, buf_gmax, buf_gden, batch, buf_pooled);
  k_head<<<N_GRAPH,64,0,stream>>>(buf_pooled, Wh1, bh1, Wh2, bh2, out);
}

// Round 9
// 698.548 us; speedup vs baseline: 1.0354x; 1.0354x over previous
//
#include <hip/hip_runtime.h>
#include <hip/hip_bf16.h>
#include <math.h>

#define N_NODES 20000
#define N_EDGES 320000
#define N_GRAPH 16
#define HID 256
#define NLAYER 4
#define NHEAD 4
#define DHEAD 64
#define EHID 16
#define NODE_DIMC 1280
#define EMLP_BLOCKS 1250   /* 1250*256 == 320000 exactly */
#define XLRS 512           /* stride of combined xl|xr buffer (in elements) */
#define TABN 4096          /* ep lookup-table knots (rows = TABN+1); nearest-knot lookup */

typedef short short8 __attribute__((ext_vector_type(8)));
typedef float f32x4 __attribute__((ext_vector_type(4)));

__device__ __forceinline__ float4 ld4(const float* p){ return *reinterpret_cast<const float4*>(p); }
__device__ __forceinline__ void st4(float* p, float4 v){ *reinterpret_cast<float4*>(p) = v; }
__device__ __forceinline__ float geluf(float x){ return 0.5f*x*(1.0f+erff(x*0.70710678118654752440f)); }
__device__ __forceinline__ float wsum64(float v){
  #pragma unroll
  for(int o=32;o;o>>=1) v += __shfl_xor(v,o,64);
  return v;
}
__device__ __forceinline__ float wmax64(float v){
  #pragma unroll
  for(int o=32;o;o>>=1) v = fmaxf(v, __shfl_xor(v,o,64));
  return v;
}
__device__ __forceinline__ int lbound(const int* __restrict__ a, int val){
  int lo=0, hi=N_NODES;
  while(lo<hi){ int mid=(lo+hi)>>1; if(a[mid]<val) lo=mid+1; else hi=mid; }
  return lo;
}
__device__ __forceinline__ short cvt_bf16(float f){
  __hip_bfloat16 h = __float2bfloat16(f);
  return *reinterpret_cast<short*>(&h);
}
__device__ __forceinline__ float bf2f(short s){
  return __uint_as_float(((unsigned)(unsigned short)s) << 16);
}
__device__ __forceinline__ float4 cvt4(short4 s){
  float4 r; r.x=bf2f(s.x); r.y=bf2f(s.y); r.z=bf2f(s.z); r.w=bf2f(s.w); return r;
}
__device__ __forceinline__ short4 f2s4(float4 v){
  short4 s; s.x=cvt_bf16(v.x); s.y=cvt_bf16(v.y); s.z=cvt_bf16(v.z); s.w=cvt_bf16(v.w); return s;
}
// async global->LDS, 16B per lane; LDS dest is wave-uniform base + lane*16
__device__ __forceinline__ void glds16(const short* g, short* l){
  __builtin_amdgcn_global_load_lds((const __attribute__((address_space(1))) void*)g,
                                   (__attribute__((address_space(3))) void*)l, 16, 0, 0);
}

// ---------------- fused weight prep + zero + x->bf16 (replaces 7 kernels) ----------------
// seg0 W_in_t 327680 | seg1 Wlr_t 524288 | seg2 Wg1_t 32768 | seg3 blr 2048 | seg4 W2e 16384
// seg5 be 1024 | seg6 zero cursor 20000 | seg7 zero pooled 4096 | seg8 xcvt 6400000 (short4 units)
#define PREP_W  904192
#define PREP_Z1 924192
#define PREP_Z2 928288
#define PREP_TOTAL 7328288
__global__ __launch_bounds__(256) void k_prep(const float* __restrict__ W_in, const float* __restrict__ Wl,
    const float* __restrict__ Wr, const float* __restrict__ Wg1, const float* __restrict__ bl,
    const float* __restrict__ br, const float* __restrict__ W2, const float* __restrict__ b2,
    const float* __restrict__ We, const float* __restrict__ x,
    short* __restrict__ W_in_t, short* __restrict__ Wlr_t, short* __restrict__ Wg1_t,
    float* __restrict__ blr, float* __restrict__ W2e, float* __restrict__ be,
    int* __restrict__ cursor, float* __restrict__ pooled, short* __restrict__ xb){
  int idx = blockIdx.x*256 + threadIdx.x;
  if(idx >= PREP_Z2){
    int t = idx - PREP_Z2;             // 6.4M float4s of x
    float4 v = ld4(x + (long)t*4);
    *(short4*)(xb + (long)t*4) = f2s4(v);
  } else if(idx < 327680){
    int n = idx / 1280, k = idx - n*1280;
    W_in_t[idx] = cvt_bf16(W_in[(long)k*256 + n]);
  } else if(idx < 851968){
    int t = idx - 327680;
    int l = t >> 17; int rem = t & 131071; int n = rem >> 8, k = rem & 255;
    const float* W = (n < 256) ? (Wl + (long)l*65536 + (long)k*256 + n)
                               : (Wr + (long)l*65536 + (long)k*256 + (n-256));
    Wlr_t[t] = cvt_bf16(*W);
  } else if(idx < 884736){
    int t = idx - 851968;
    int n = t >> 8, k = t & 255;
    Wg1_t[t] = cvt_bf16(Wg1[(long)k*128 + n]);
  } else if(idx < 886784){
    int t = idx - 884736;
    int l = t >> 9, c = t & 511;
    blr[t] = (c < 256) ? bl[l*256 + c] : br[l*256 + c - 256];
  } else if(idx < 903168){
    int t = idx - 886784;
    int l = t >> 12; int rem = t & 4095; int k = rem >> 8, dd = rem & 255;
    float s = 0.f;
    #pragma unroll
    for(int j=0;j<16;j++) s += W2[k*16+j]*We[l*4096 + j*256 + dd];
    W2e[t] = s;
  } else if(idx < PREP_W){
    int t = idx - 903168;
    int l = t >> 8, dd = t & 255;
    float s = 0.f;
    #pragma unroll
    for(int j=0;j<16;j++) s += b2[j]*We[l*4096 + j*256 + dd];
    be[t] = s;
  } else if(idx < PREP_Z1){
    cursor[idx - PREP_W] = 0;
  } else {
    pooled[idx - PREP_Z1] = 0.f;
  }
}

// ---------------- ep lookup table ----------------
__global__ __launch_bounds__(256) void k_etab(const float* __restrict__ W1, const float* __restrict__ b1,
                      const float* __restrict__ W2e, const float* __restrict__ be,
                      short* __restrict__ tab){
  __shared__ float t[16];
  int idx = blockIdx.x, l = blockIdx.y, d = threadIdx.x;
  if(d < 16) t[d] = geluf(((float)idx*(1.0f/TABN))*W1[d] + b1[d]);
  __syncthreads();
  float s = be[l*256 + d];
  #pragma unroll
  for(int k=0;k<16;k++) s += t[k]*W2e[(l*16+k)*256 + d];
  tab[((long)l*(TABN+1) + idx)*256 + d] = cvt_bf16(s);
}

// ---------------- pipelined bf16 GEMM (async, prefetch depth 2, triple buffer, counted vmcnt) ----------------
// OUTB: 0 = fp32 C, 1 = bf16 C via LDS-coalesced epilogue, 2 = gate mode
// 48KB LDS -> 3 blocks/CU: co-resident blocks hide the barrier drains (m114). This config is
// the verified optimum across prefetch depth (r2), tile shape (r5), staging (r6), barriers (r8).
template<int OUTB>
__global__ __launch_bounds__(256) void k_gemm_p(const short* __restrict__ A,
    const short* __restrict__ Bt, const float* __restrict__ bias,
    float* __restrict__ Cf, short* __restrict__ Cb,
    const float* __restrict__ Wg2, const float* __restrict__ bg2, float* __restrict__ gate,
    int M, int K, int ldc){
  __shared__ short smem[24576];   // 48KB: As = smem[0..12287] (3 bufs), Bs = smem[12288..24575]
  short* Asb = smem;
  short* Bsb = smem + 12288;
  int tid = threadIdx.x;
  int w = tid>>6, lane = tid&63;
  int g = lane>>4, m = lane&15;
  int bm = blockIdx.x*128, bn = blockIdx.y*128;
  int crow = lane>>2;
  int coff = (lane&3)*8;
  int ar0 = bm + (w*2+0)*16 + crow; ar0 = ar0 < M ? ar0 : M-1;
  int ar1 = bm + (w*2+1)*16 + crow; ar1 = ar1 < M ? ar1 : M-1;
  const short* Ap0 = A + (long)ar0*K + coff;
  const short* Ap1 = A + (long)ar1*K + coff;
  const short* Bp0 = Bt + (long)(bn + (w*2+0)*16 + crow)*K + coff;
  const short* Bp1 = Bt + (long)(bn + (w*2+1)*16 + crow)*K + coff;
  short* As0 = Asb + (w*2+0)*512; short* As1 = Asb + (w*2+1)*512;
  short* Bs0 = Bsb + (w*2+0)*512; short* Bs1 = Bsb + (w*2+1)*512;
  const int bufstride = 128*32;
  f32x4 acc[2][8];
  #pragma unroll
  for(int i=0;i<2;i++)
    #pragma unroll
    for(int j=0;j<8;j++) acc[i][j] = (f32x4){0.f,0.f,0.f,0.f};
  int niter = K >> 5;
  // prologue: stage iters 0 and 1
  glds16(Ap0, As0); glds16(Ap1, As1); glds16(Bp0, Bs0); glds16(Bp1, Bs1);
  if(niter > 1){
    glds16(Ap0+32, As0+bufstride); glds16(Ap1+32, As1+bufstride);
    glds16(Bp0+32, Bs0+bufstride); glds16(Bp1+32, Bs1+bufstride);
  }
  for(int i=0;i<niter;i++){
    int cur = i % 3;
    if(i+2 < niter){
      int k = (i+2)<<5;
      int nb = (i+2) % 3;
      glds16(Ap0 + k, As0 + nb*bufstride);
      glds16(Ap1 + k, As1 + nb*bufstride);
      glds16(Bp0 + k, Bs0 + nb*bufstride);
      glds16(Bp1 + k, Bs1 + nb*bufstride);
      __builtin_amdgcn_s_waitcnt(0x0F78);   // vmcnt(8): groups i+1,i+2 in flight; group i done
    } else if(i+1 < niter){
      __builtin_amdgcn_s_waitcnt(0x0F74);   // vmcnt(4): group i+1 in flight; group i done
    } else {
      __builtin_amdgcn_s_waitcnt(0x0F70);   // vmcnt(0): last group done
    }
    __builtin_amdgcn_s_barrier();
    const short* ab = Asb + cur*bufstride;
    const short* bb = Bsb + cur*bufstride;
    short8 a0 = *(const short8*)&ab[(w*32 + m)*32 + g*8];
    short8 a1 = *(const short8*)&ab[(w*32 + 16 + m)*32 + g*8];
    #pragma unroll
    for(int j=0;j<8;j++){
      short8 bf = *(const short8*)&bb[(j*16 + m)*32 + g*8];
      acc[0][j] = __builtin_amdgcn_mfma_f32_16x16x32_bf16(a0, bf, acc[0][j], 0,0,0);
      acc[1][j] = __builtin_amdgcn_mfma_f32_16x16x32_bf16(a1, bf, acc[1][j], 0,0,0);
    }
    __builtin_amdgcn_s_barrier();
  }
  if(OUTB == 2){
    float bg2v = bg2[0];
    #pragma unroll
    for(int mi=0;mi<2;mi++){
      float part[4] = {0.f,0.f,0.f,0.f};
      #pragma unroll
      for(int j=0;j<8;j++){
        int col = j*16 + m;
        float wg = Wg2[col];
        float bv = bias[col];
        #pragma unroll
        for(int r=0;r<4;r++) part[r] += tanhf(acc[mi][j][r] + bv) * wg;
      }
      #pragma unroll
      for(int r=0;r<4;r++){
        #pragma unroll
        for(int o=1;o<16;o<<=1) part[r] += __shfl_xor(part[r], o, 16);
      }
      if(m == 0){
        #pragma unroll
        for(int r=0;r<4;r++){
          int row = bm + w*32 + mi*16 + g*4 + r;
          if(row < M) gate[row] = part[r] + bg2v;
        }
      }
    }
  } else if(OUTB == 1){
    // scatter into LDS [128][132] bf16 (values identical to old path), then coalesced stores
    #pragma unroll
    for(int mi=0;mi<2;mi++){
      int rl0 = w*32 + mi*16 + g*4;
      #pragma unroll
      for(int j=0;j<8;j++){
        int col = j*16 + m;
        float bv = bias[bn + col];
        #pragma unroll
        for(int r=0;r<4;r++)
          smem[(rl0 + r)*132 + col] = cvt_bf16(acc[mi][j][r] + bv);
      }
    }
    __syncthreads();
    int lr = tid >> 4, lc = (tid & 15)*8;
    #pragma unroll
    for(int p=0;p<8;p++){
      int row = bm + p*16 + lr;
      if(row < M){
        short8 v = *(const short8*)&smem[(p*16 + lr)*132 + lc];
        *(short8*)&Cb[(long)row*ldc + bn + lc] = v;
      }
    }
  } else {
    #pragma unroll
    for(int mi=0;mi<2;mi++){
      int r0 = bm + w*32 + mi*16 + g*4;
      #pragma unroll
      for(int j=0;j<8;j++){
        int col = bn + j*16 + m;
        float bv = bias[col];
        #pragma unroll
        for(int r=0;r<4;r++){
          int row = r0 + r;
          if(row < M) Cf[(long)row*ldc + col] = acc[mi][j][r] + bv;
        }
      }
    }
  }
}

// ---------------- LayerNorm + GELU (input proj epilogue); writes fp32 h + bf16 h ----------------
__global__ __launch_bounds__(256) void k_ln_gelu(const float* __restrict__ in, const float* __restrict__ g,
                          const float* __restrict__ b, float* __restrict__ out, short* __restrict__ outb){
  int gw = (int)((blockIdx.x * blockDim.x + threadIdx.x) >> 6);
  int lane = threadIdx.x & 63;
  if (gw >= N_NODES) return;
  long base = (long)gw*HID + lane*4;
  float4 v = ld4(in + base);
  float mu = wsum64(v.x+v.y+v.z+v.w) * (1.0f/HID);
  float dx=v.x-mu, dy=v.y-mu, dz=v.z-mu, dw=v.w-mu;
  float var = wsum64(dx*dx+dy*dy+dz*dz+dw*dw) * (1.0f/HID);
  float r = rsqrtf(var + 1e-5f);
  float4 gg = ld4(g + lane*4), bb = ld4(b + lane*4);
  float4 o;
  o.x = geluf(dx*r*gg.x + bb.x);
  o.y = geluf(dy*r*gg.y + bb.y);
  o.z = geluf(dz*r*gg.z + bb.z);
  o.w = geluf(dw*r*gg.w + bb.w);
  st4(out + base, o);
  *(short4*)(outb + base) = f2s4(o);
}

// ---------------- edge MLP t-partials only (mean path) ----------------
__global__ __launch_bounds__(256) void k_edge_mlp(const float* __restrict__ ea, const float* __restrict__ W1,
                          const float* __restrict__ b1, float* __restrict__ epart){
  __shared__ float sW1[16], sB1[16];
  __shared__ float red[4][16];
  int tid = threadIdx.x;
  if(tid<16){ sW1[tid]=W1[tid]; sB1[tid]=b1[tid]; }
  __syncthreads();
  int e = blockIdx.x*256 + tid;
  float u = ea[e];
  int wv = tid>>6, lane = tid&63;
  #pragma unroll
  for(int j=0;j<16;j++){
    float t = geluf(u*sW1[j] + sB1[j]);
    float r = wsum64(t);
    if(lane == 0) red[wv][j] = r;
  }
  __syncthreads();
  if(tid < 16) epart[blockIdx.x*16 + tid] = red[0][tid]+red[1][tid]+red[2][tid]+red[3][tid];
}

// ---------------- reduce t-partials -> e_mean -> ep_loop[l] ----------------
__global__ __launch_bounds__(256) void k_const(const float* __restrict__ epart, const float* __restrict__ W2,
                       const float* __restrict__ b2, const float* __restrict__ We,
                       float* __restrict__ eploop){
  __shared__ float red[16][16];
  __shared__ float em[16];
  int tid = threadIdx.x;
  int j = tid & 15, p0 = tid >> 4;
  float s = 0.f;
  for(int p = p0; p < EMLP_BLOCKS; p += 16) s += epart[p*16 + j];
  red[p0][j] = s;
  __syncthreads();
  if(tid < 16){
    #pragma unroll
    for(int k=0;k<16;k++){
      float t = 0.f;
      #pragma unroll
      for(int q=0;q<16;q++) t += red[q][k];
      red[0][k] = t * (1.0f/N_EDGES);
    }
  }
  __syncthreads();
  if(tid < 16){
    float acc = b2[tid];
    #pragma unroll
    for(int k=0;k<16;k++) acc += red[0][k]*W2[k*16 + tid];
    em[tid] = acc;
  }
  __syncthreads();
  for(int l=0;l<NLAYER;l++){
    float acc = 0.f;
    #pragma unroll
    for(int k=0;k<16;k++) acc += em[k]*We[l*EHID*HID + k*HID + tid];
    eploop[l*HID + tid] = acc;
  }
}

__global__ __launch_bounds__(256) void k_csr_count(const int* __restrict__ ei, int* __restrict__ counts){
  int e = blockIdx.x*256 + threadIdx.x;
  if(e < N_EDGES) atomicAdd(&counts[ei[N_EDGES + e]], 1);
}

__global__ __launch_bounds__(1024) void k_csr_scan(const int* __restrict__ counts, int* __restrict__ offs,
                                                   int* __restrict__ cursor){
  __shared__ int part[1024];
  int t = threadIdx.x;
  const int chunk = (N_NODES + 1023) / 1024;
  int b0 = t * chunk;
  int s = 0;
  for(int i=0;i<chunk;i++){ int idx=b0+i; if(idx<N_NODES) s += counts[idx]; }
  part[t] = s;
  __syncthreads();
  for(int off=1; off<1024; off<<=1){
    int v = part[t];
    int add = (t>=off) ? part[t-off] : 0;
    __syncthreads();
    part[t] = v + add;
    __syncthreads();
  }
  int run = (t==0) ? 0 : part[t-1];
  for(int i=0;i<chunk;i++){
    int idx = b0+i;
    if(idx < N_NODES){
      int c = counts[idx];
      offs[idx] = run; cursor[idx] = run;
      run += c;
    }
  }
  if(t == 1023) offs[N_NODES] = part[1023];
}

// meta stores BYTE offsets: x = src*1024 (xlr row), y = i0*512 (tab row).
__global__ __launch_bounds__(256) void k_csr_fill(const int* __restrict__ ei, const float* __restrict__ ea,
                          int* __restrict__ cursor, int2* __restrict__ meta){
  int e = blockIdx.x*256 + threadIdx.x;
  if(e >= N_EDGES) return;
  int d = ei[N_EDGES + e];
  int pos = atomicAdd(&cursor[d], 1);
  float u = ea[e];
  int i0 = (int)(u * (float)TABN + 0.5f);
  meta[pos] = make_int2(ei[e] << 10, i0 << 9);
}

// ---------------- fused per-layer: 4-deep pipelined gather + nearest-knot ep + batched online softmax ----------------
__global__ __launch_bounds__(256) void k_layer(
    const short* __restrict__ xlr, float* __restrict__ h, short* __restrict__ hb,
    const short* __restrict__ tab_l,
    const float* __restrict__ eploop_l, const float* __restrict__ att_l,
    const int* __restrict__ offs, const int2* __restrict__ meta,
    const float* __restrict__ bconv_l, const float* __restrict__ g_l,
    const float* __restrict__ b_l){
  int tid = threadIdx.x;
  int lane = tid & 63;
  int d = blockIdx.x*4 + (tid >> 6);
  float4 at4 = ld4(att_l + lane*4);
  float4 epl = ld4(eploop_l + lane*4);
  const short4* xp = (const short4*)(xlr + (long)d*XLRS);
  float4 xld = cvt4(xp[lane]);
  float4 xr4 = cvt4(xp[64 + lane]);
  long hbase = (long)d*HID + lane*4;
  float4 h4 = ld4(h + hbase);
  int beg = offs[d], end = offs[d+1];

  const char* xlrb = (const char*)xlr + (lane<<3);
  const char* tabb = (const char*)tab_l + (lane<<3);

  short4 xsb0, xsb1, xsb2, xsb3, ta0, ta1, ta2, ta3;
  auto issue = [&](short4 &xsb, short4 &ta, int j){
    int2 mm = meta[j];
    xsb = *(const short4*)(xlrb + mm.x);
    ta  = *(const short4*)(tabb + mm.y);
  };
  auto logit = [&](short4 xsbv, short4 tav, float4 &xsf)->float{
    xsf = cvt4(xsbv);
    float4 t0 = cvt4(tav);
    float mx = xsf.x + xr4.x + t0.x; mx = fmaxf(mx, 0.2f*mx);
    float my = xsf.y + xr4.y + t0.y; my = fmaxf(my, 0.2f*my);
    float mz = xsf.z + xr4.z + t0.z; mz = fmaxf(mz, 0.2f*mz);
    float mw = xsf.w + xr4.w + t0.w; mw = fmaxf(mw, 0.2f*mw);
    float q = mx*at4.x + my*at4.y + mz*at4.z + mw*at4.w;
    q += __shfl_xor(q, 1, 16);
    q += __shfl_xor(q, 2, 16);
    q += __shfl_xor(q, 4, 16);
    q += __shfl_xor(q, 8, 16);
    return q;
  };

  float m_run, den;
  float4 acc;
  auto upd = [&](float q, float4 xs){
    if(q > m_run + 8.f){
      float sc = __expf(m_run - q);
      den *= sc;
      acc.x *= sc; acc.y *= sc; acc.z *= sc; acc.w *= sc;
      m_run = q;
    }
    float pe = __expf(q - m_run);
    den += pe;
    acc.x += pe*xs.x;
    acc.y += pe*xs.y;
    acc.z += pe*xs.z;
    acc.w += pe*xs.w;
  };

  int i = beg;
  if(beg < end){
    int e1 = (beg+1 < end) ? beg+1 : end-1;
    int e2 = (beg+2 < end) ? beg+2 : end-1;
    int e3 = (beg+3 < end) ? beg+3 : end-1;
    issue(xsb0, ta0, beg);
    issue(xsb1, ta1, e1);
    issue(xsb2, ta2, e2);
    issue(xsb3, ta3, e3);
  }
  float ax = xld.x + xr4.x + epl.x; ax = fmaxf(ax, 0.2f*ax);
  float ay = xld.y + xr4.y + epl.y; ay = fmaxf(ay, 0.2f*ay);
  float az = xld.z + xr4.z + epl.z; az = fmaxf(az, 0.2f*az);
  float aw = xld.w + xr4.w + epl.w; aw = fmaxf(aw, 0.2f*aw);
  float p = ax*at4.x + ay*at4.y + az*at4.z + aw*at4.w;
  p += __shfl_xor(p, 1, 16);
  p += __shfl_xor(p, 2, 16);
  p += __shfl_xor(p, 4, 16);
  p += __shfl_xor(p, 8, 16);
  m_run = p;
  den = 1.f;
  acc = xld;

  for(; i+3 < end; i += 4){
    float4 xs0, xs1, xs2, xs3;
    float q0 = logit(xsb0, ta0, xs0);
    float q1 = logit(xsb1, ta1, xs1);
    float q2 = logit(xsb2, ta2, xs2);
    float q3 = logit(xsb3, ta3, xs3);
    int j0 = (i+4 < end) ? i+4 : end-1;
    int j1 = (i+5 < end) ? i+5 : end-1;
    int j2 = (i+6 < end) ? i+6 : end-1;
    int j3 = (i+7 < end) ? i+7 : end-1;
    issue(xsb0, ta0, j0);
    issue(xsb1, ta1, j1);
    issue(xsb2, ta2, j2);
    issue(xsb3, ta3, j3);
    float pmax = fmaxf(fmaxf(q0,q1), fmaxf(q2,q3));
    if(pmax > m_run + 8.f){
      float sc = __expf(m_run - pmax);
      den *= sc;
      acc.x *= sc; acc.y *= sc; acc.z *= sc; acc.w *= sc;
      m_run = pmax;
    }
    float p0 = __expf(q0 - m_run), p1 = __expf(q1 - m_run);
    float p2 = __expf(q2 - m_run), p3 = __expf(q3 - m_run);
    den += (p0+p1)+(p2+p3);
    acc.x += p0*xs0.x + p1*xs1.x + p2*xs2.x + p3*xs3.x;
    acc.y += p0*xs0.y + p1*xs1.y + p2*xs2.y + p3*xs3.y;
    acc.z += p0*xs0.z + p1*xs1.z + p2*xs2.z + p3*xs3.z;
    acc.w += p0*xs0.w + p1*xs1.w + p2*xs2.w + p3*xs3.w;
  }
  int rem = end - i;
  if(rem > 0){ float4 xs; float q = logit(xsb0, ta0, xs); upd(q, xs); }
  if(rem > 1){ float4 xs; float q = logit(xsb1, ta1, xs); upd(q, xs); }
  if(rem > 2){ float4 xs; float q = logit(xsb2, ta2, xs); upd(q, xs); }

  float inv = 1.f/den;
  float4 bc4 = ld4(bconv_l + lane*4);
  float4 gg4 = ld4(g_l + lane*4);
  float4 bb4 = ld4(b_l + lane*4);
  float yx = geluf(acc.x*inv + bc4.x) + h4.x;
  float yy = geluf(acc.y*inv + bc4.y) + h4.y;
  float yz = geluf(acc.z*inv + bc4.z) + h4.z;
  float yw = geluf(acc.w*inv + bc4.w) + h4.w;
  float mu = wsum64(yx+yy+yz+yw) * (1.0f/HID);
  float dx=yx-mu, dy=yy-mu, dz=yz-mu, dw=yw-mu;
  float var = wsum64(dx*dx+dy*dy+dz*dz+dw*dw) * (1.0f/HID);
  float r = rsqrtf(var + 1e-5f);
  float4 o;
  o.x = dx*r*gg4.x + bb4.x;
  o.y = dy*r*gg4.y + bb4.y;
  o.z = dz*r*gg4.z + bb4.z;
  o.w = dw*r*gg4.w + bb4.w;
  st4(h + hbase, o);
  *(short4*)(hb + hbase) = f2s4(o);
}

// ---------------- per-graph softmax stats ----------------
__global__ __launch_bounds__(256) void k_gsm(const float* __restrict__ gate, const int* __restrict__ batch,
                     float* __restrict__ gmax, float* __restrict__ gden){
  __shared__ int sr[2];
  __shared__ float red[4];
  int g = blockIdx.x, tid = threadIdx.x;
  if(tid == 0){ sr[0] = lbound(batch, g); sr[1] = lbound(batch, g+1); }
  __syncthreads();
  int r0 = sr[0], r1 = sr[1];
  float mx = -3.4e38f;
  for(int v = r0 + tid; v < r1; v += 256) mx = fmaxf(mx, gate[v]);
  mx = wmax64(mx);
  if((tid&63)==0) red[tid>>6] = mx;
  __syncthreads();
  float m = fmaxf(fmaxf(red[0],red[1]), fmaxf(red[2],red[3]));
  float s = 0.f;
  for(int v = r0 + tid; v < r1; v += 256) s += __expf(gate[v] - m);
  s = wsum64(s);
  if((tid&63)==0) red[tid>>6] = s;
  __syncthreads();
  if(tid == 0){
    gmax[g] = m;
    gden[g] = red[0]+red[1]+red[2]+red[3];
  }
}

// ---------------- pooled[g] += w[v]*h[v] ----------------
__global__ __launch_bounds__(256) void k_gpool(const float* __restrict__ h, const float* __restrict__ gate,
                       const float* __restrict__ gmax, const float* __restrict__ gden,
                       const int* __restrict__ batch, float* __restrict__ pooled){
  __shared__ int sr[2];
  int g = blockIdx.y, c = threadIdx.x;
  if(c == 0){ sr[0] = lbound(batch, g); sr[1] = lbound(batch, g+1); }
  __syncthreads();
  int r0 = sr[0], r1 = sr[1];
  float m = gmax[g], inv = 1.f/gden[g];
  float acc = 0.f;
  for(int v = r0 + blockIdx.x; v < r1; v += 16){
    float w = __expf(gate[v] - m) * inv;
    acc += w * h[(long)v*HID + c];
  }
  atomicAdd(&pooled[g*HID + c], acc);
}

__global__ __launch_bounds__(64) void k_head(const float* __restrict__ pooled, const float* __restrict__ Wh1,
                      const float* __restrict__ bh1, const float* __restrict__ Wh2,
                      const float* __restrict__ bh2, float* __restrict__ out){
  __shared__ float sp[HID];
  int b = blockIdx.x, t = threadIdx.x;
  #pragma unroll
  for(int i=0;i<4;i++) sp[t + i*64] = pooled[b*HID + t + i*64];
  __syncthreads();
  float acc = bh1[t];
  #pragma unroll 8
  for(int k=0;k<HID;k++) acc += sp[k]*Wh1[k*64 + t];
  float g = geluf(acc);
  float contrib = g * Wh2[t];
  float r = wsum64(contrib);
  if(t==0) out[b] = r + bh2[0];
}

extern "C" void kernel_launch(void* const* d_in, const int* in_sizes, int n_in,
                              void* d_out, int out_size, void* d_ws, size_t ws_size,
                              hipStream_t stream) {
  const float* x        = (const float*)d_in[0];
  const float* edge_attr= (const float*)d_in[1];
  const float* W_in     = (const float*)d_in[2];
  const float* b_in     = (const float*)d_in[3];
  const float* ln_in_g  = (const float*)d_in[4];
  const float* ln_in_b  = (const float*)d_in[5];
  const float* W_e1     = (const float*)d_in[6];
  const float* b_e1     = (const float*)d_in[7];
  const float* W_e2     = (const float*)d_in[8];
  const float* b_e2     = (const float*)d_in[9];
  const float* Wl       = (const float*)d_in[10];
  const float* bl       = (const float*)d_in[11];
  const float* Wr       = (const float*)d_in[12];
  const float* br       = (const float*)d_in[13];
  const float* att      = (const float*)d_in[14];
  const float* We       = (const float*)d_in[15];
  const float* bconv    = (const float*)d_in[16];
  const float* ln_g     = (const float*)d_in[17];
  const float* ln_b     = (const float*)d_in[18];
  const float* Wg1      = (const float*)d_in[19];
  const float* bg1      = (const float*)d_in[20];
  const float* Wg2      = (const float*)d_in[21];
  const float* bg2      = (const float*)d_in[22];
  const float* Wh1      = (const float*)d_in[23];
  const float* bh1      = (const float*)d_in[24];
  const float* Wh2      = (const float*)d_in[25];
  const float* bh2      = (const float*)d_in[26];
  const int*   ei       = (const int*)d_in[27];
  const int*   batch    = (const int*)d_in[28];
  float* out = (float*)d_out;

  // ---- workspace layout (float offsets). x_bf16 (10.24M..23.04M) is dead after input GEMM;
  // only buf_xlr / buf_tab / buf_hb (first written after it) overlap that region.
  float* ws = (float*)d_ws;
  float* buf_h     = ws;                         // 0 .. 5.12M
  float* buf_t     = ws + 5120000;               // 5.12M .. 10.24M (input-proj tmp)
  short* buf_xlr   = (short*)(ws + 10240000);    // N*512 bf16
  short* x_bf16    = (short*)(ws + 10240000);    // 25.6M shorts -> ends 23.04M
  short* buf_tab   = (short*)(ws + 15360000);    // 4*4097*256 bf16
  short* buf_hb    = (short*)(ws + 17460000);    // N*256 bf16
  float* buf_eploop= ws + 23040000;              // 1024
  float* buf_gate  = ws + 23041024;              // 20000
  float* buf_gmax  = ws + 23061024;              // 16
  float* buf_gden  = ws + 23061040;              // 16
  float* buf_pooled= ws + 23061056;              // 4096
  float* buf_epart = ws + 23065200;              // 20000
  int*   csr_offs  = (int*)(ws + 23085200);      // 20001
  int*   csr_cursor= (int*)(ws + 23105204);      // 20000
  int2*  csr_meta  = (int2*)(ws + 23125204);     // 320000 int2
  short* W_in_t    = (short*)(ws + 23765204);    // 327,680 shorts
  short* Wlr_t     = (short*)(ws + 23929044);    // 524,288 shorts
  short* Wg1_t     = (short*)(ws + 24191188);    // 32,768 shorts
  float* buf_blr   = ws + 24207572;              // 2048
  float* buf_W2e   = ws + 24209620;              // 16384
  float* buf_be    = ws + 24226004;              // 1024

  // fused weight prep + zero + x->bf16 (replaces prep/zero/xcvt)
  k_prep<<<(PREP_TOTAL+255)/256,256,0,stream>>>(W_in, Wl, Wr, Wg1, bl, br, W_e2, b_e2, We, x,
                                                W_in_t, Wlr_t, Wg1_t, buf_blr, buf_W2e, buf_be,
                                                csr_cursor, buf_pooled, x_bf16);
  k_csr_count<<<(N_EDGES+255)/256,256,0,stream>>>(ei, csr_cursor);
  k_csr_scan<<<1,1024,0,stream>>>(csr_cursor, csr_offs, csr_cursor);
  k_csr_fill<<<(N_EDGES+255)/256,256,0,stream>>>(ei, edge_attr, csr_cursor, csr_meta);

  // input proj, epilogue
  k_gemm_p<0><<<dim3(157,2),256,0,stream>>>(x_bf16, W_in_t, b_in, buf_t, nullptr,
                                            nullptr, nullptr, nullptr, N_NODES, NODE_DIMC, 256);
  k_ln_gelu<<<(N_NODES+3)/4,256,0,stream>>>(buf_t, ln_in_g, ln_in_b, buf_h, buf_hb);
  k_etab<<<dim3(TABN+1,NLAYER),256,0,stream>>>(W_e1, b_e1, buf_W2e, buf_be, buf_tab);
  k_edge_mlp<<<EMLP_BLOCKS,256,0,stream>>>(edge_attr, W_e1, b_e1, buf_epart);
  k_const<<<1,256,0,stream>>>(buf_epart, W_e2, b_e2, We, buf_eploop);

  for(int l=0;l<NLAYER;l++){
    k_gemm_p<1><<<dim3(157,4),256,0,stream>>>(buf_hb, Wlr_t + (long)l*131072,
                       buf_blr + l*512, nullptr, buf_xlr,
                       nullptr, nullptr, nullptr, N_NODES, HID, XLRS);
    k_layer<<<5000,256,0,stream>>>(buf_xlr, buf_h, buf_hb, buf_tab + (long)l*(TABN+1)*256,
                       buf_eploop + l*HID, att + l*NHEAD*DHEAD,
                       csr_offs, csr_meta, bconv + l*HID, ln_g + l*HID, ln_b + l*HID);
  }

  // gate fused into GEMM epilogue
  k_gemm_p<2><<<dim3(157,1),256,0,stream>>>(buf_hb, Wg1_t, bg1, nullptr, nullptr,
                                            Wg2, bg2, buf_gate, N_NODES, HID, 0);
  k_gsm<<<N_GRAPH,256,0,stream>>>(buf_gate, batch, buf_gmax, buf_gden);
  dim3 gP(16, N_GRAPH);
  k_gpool<<<gP,256,0,stream>>>(buf_h, buf_gate, buf_gmax, buf_gden, batch, buf_pooled);
  k_head<<<N_GRAPH,64,0,stream>>>(buf_pooled, Wh1, bh1, Wh2, bh2, out);
}